// Round 7
// baseline (259.526 us; speedup 1.0000x reference)
//
#include <hip/hip_runtime.h>

// Problem constants (from reference setup_inputs)
#define B    128
#define H    14
#define W    14
#define C    512
#define NCLS 200
#define HW   (H * W)          // 196
#define TP_DIM 15             // t_p is [15,15,14,14]
#define SENT_OFF ((14 * TP_DIM + 14) * HW)  // sentinel template row offset

typedef float  v4f __attribute__((ext_vector_type(4)));
typedef int    v4i __attribute__((ext_vector_type(4)));

// ---------------------------------------------------------------------------
// Fused kernel v6: v5's register streaming + v4's occupancy.
//
// Post-mortem of v4 (250.3, 2 blk/CU, x re-read) vs v5 (257, 1 blk/CU,
// x in regs): v5's xr[16]+tr[4][4] cost ~160 VGPR -> 1 block/CU; the lost
// wave overlap outweighed the 51 MB x-re-read it saved. v6 keeps x in
// registers but fits 128 VGPR -> 2 blocks/CU:
//   - __launch_bounds__(512, 4): 16 waves/CU -> hard 128-VGPR cap.
//   - tail redistribution: s=192..195 go one-each to sl=12..15 (max 13 v4f
//     of x = 52 VGPR, near-perfect balance) instead of sl15 owning all 4.
//   - t_p gathered per-quad inside the loop (16-float window), not a
//     resident tr[4][4].
//   - combine uses explicit (val, idx) lexicographic tie-break since
//     per-thread s-ranges are no longer ordered by sl (first-occurrence
//     semantics of jnp.argmax preserved exactly).
//
// Ownership: block (b, quarter) = batch b, channels [q*128,+128).
//   Thread (sl = tid>>5, cg = tid&31): spatial [12*sl, 12*sl+12), plus
//   position 192+(sl-12) for sl>=12. x read exactly once grid-wide; out_x
//   stores come straight from registers. Barriers: 2. LDS: 16.5 KB.
//   XCD swizzle: quarter-blocks of batch b are blockIdx ≡ b (mod 8).
// ---------------------------------------------------------------------------
__global__ __launch_bounds__(512, 4) void fused_kernel(
        const float* __restrict__ x,
        const float* __restrict__ gt,
        const float* __restrict__ t_p,
        const float* __restrict__ ctpl,
        float*       __restrict__ out) {
    __shared__ v4f s_best[16][32];
    __shared__ v4i s_idx[16][32];
    __shared__ int s_off[128];
    __shared__ int s_cls;

    const int tid     = threadIdx.x;
    const int b       = blockIdx.x & 127;   // XCD swizzle (see header)
    const int quarter = blockIdx.x >> 7;
    const int cg      = tid & 31;           // channel group (4 ch) 0..31
    const int sl      = tid >> 5;           // spatial-slice id 0..15
    const int c0      = quarter * 128 + cg * 4;
    const int cl      = cg * 4;             // local channel base
    const bool xtra   = (sl >= 12);         // waves 6,7: own one tail position
    const int  se     = 192 + (sl - 12);    // tail position (sl>=12 only)
    const int  sbeg   = 12 * sl;

    const float* __restrict__ xp = x + (size_t)b * HW * C + c0;

    // ---------------- Phase 1: x slice -> registers, in-thread argmax ------
    v4f xr[12];
#pragma unroll
    for (int k = 0; k < 12; ++k)
        xr[k] = *(const v4f*)(xp + (size_t)(sbeg + k) * C);
    v4f xe = (v4f){0.f, 0.f, 0.f, 0.f};
    if (xtra) xe = *(const v4f*)(xp + (size_t)se * C);

    v4f best = xr[0];
    v4i bidx = (v4i){sbeg, sbeg, sbeg, sbeg};
#pragma unroll
    for (int k = 1; k < 12; ++k) {
        const int s = sbeg + k;
        v4f v = xr[k];
        if (v.x > best.x) { best.x = v.x; bidx.x = s; }  // strict > = first occ.
        if (v.y > best.y) { best.y = v.y; bidx.y = s; }
        if (v.z > best.z) { best.z = v.z; bidx.z = s; }
        if (v.w > best.w) { best.w = v.w; bidx.w = s; }
    }
    if (xtra) {   // se > all base positions of this thread; processed last
        if (xe.x > best.x) { best.x = xe.x; bidx.x = se; }
        if (xe.y > best.y) { best.y = xe.y; bidx.y = se; }
        if (xe.z > best.z) { best.z = xe.z; bidx.z = se; }
        if (xe.w > best.w) { best.w = xe.w; bidx.w = se; }
    }
    s_best[sl][cg] = best;
    s_idx[sl][cg]  = bidx;
    __syncthreads();

    // ---------------- Combine (tid<32) + gt-argmax (wave 1) ----------------
    if (tid < 32) {
        v4f cb = s_best[0][tid];
        v4i ci = s_idx[0][tid];
#pragma unroll
        for (int k = 1; k < 16; ++k) {
            // explicit lexicographic tie-break: (val >) or (val ==, idx <)
            v4f p = s_best[k][tid];
            v4i q = s_idx[k][tid];
            if (p.x > cb.x || (p.x == cb.x && q.x < ci.x)) { cb.x = p.x; ci.x = q.x; }
            if (p.y > cb.y || (p.y == cb.y && q.y < ci.y)) { cb.y = p.y; ci.y = q.y; }
            if (p.z > cb.z || (p.z == cb.z && q.z < ci.z)) { cb.z = p.z; ci.z = q.z; }
            if (p.w > cb.w || (p.w == cb.w && q.w < ci.w)) { cb.w = p.w; ci.w = q.w; }
        }
        v4i o;
        o.x = (cb.x == 0.0f) ? SENT_OFF : ((ci.x / W) * TP_DIM + (ci.x % W)) * HW;
        o.y = (cb.y == 0.0f) ? SENT_OFF : ((ci.y / W) * TP_DIM + (ci.y % W)) * HW;
        o.z = (cb.z == 0.0f) ? SENT_OFF : ((ci.z / W) * TP_DIM + (ci.z % W)) * HW;
        o.w = (cb.w == 0.0f) ? SENT_OFF : ((ci.w / W) * TP_DIM + (ci.w % W)) * HW;
        *(v4i*)&s_off[tid * 4] = o;
    } else if (tid >= 64 && tid < 128) {
        // wave 1: class argmax over gt[b], index-min tie-break
        const int lane = tid - 64;
        const float* __restrict__ g = gt + (size_t)b * NCLS;
        float gb = -__builtin_inff();
        int   gi = NCLS;
        for (int i = lane; i < NCLS; i += 64) {   // ascending per lane
            float v = g[i];
            if (v > gb) { gb = v; gi = i; }       // keeps smallest index
        }
#pragma unroll
        for (int d = 1; d < 64; d <<= 1) {
            float ov = __shfl_xor(gb, d);
            int   oi = __shfl_xor(gi, d);
            if (ov > gb || (ov == gb && oi < gi)) { gb = ov; gi = oi; }
        }
        if (lane == 0) s_cls = gi;
    }
    __syncthreads();

    // ---------------- Phase 2: per-quad t gather, stream out ---------------
    const int klass = s_cls;
    const v4i off = *(const v4i*)&s_off[cl];   // t_p rows for c0..c0+3

    const size_t plane = (size_t)B * HW * C;
    const float* __restrict__ ctp = ctpl + (size_t)klass * HW * C;

#pragma unroll
    for (int m = 0; m < 3; ++m) {           // quad m: s0 = sbeg + 4m
        const int s0 = sbeg + 4 * m;
        // per-quad t_p segments (16-B aligned: sbeg ≡ 0 mod 4), short-lived
        v4f t0 = *(const v4f*)(t_p + off.x + s0);
        v4f t1 = *(const v4f*)(t_p + off.y + s0);
        v4f t2 = *(const v4f*)(t_p + off.z + s0);
        v4f t3 = *(const v4f*)(t_p + off.w + s0);

        const size_t base = ((size_t)b * HW + s0) * C + c0;
        const float* __restrict__ cp = ctp + (size_t)s0 * C + c0;
        float* __restrict__ out_m = out + base;
        float* __restrict__ out_x = out + plane + base;
        float* __restrict__ out_t = out + 2 * plane + base;

#pragma unroll
        for (int i = 0; i < 4; ++i) {
            v4f xv = xr[4 * m + i];          // registers — no load
            v4f ct = *(const v4f*)(cp + (size_t)i * C);
            v4f tt;                          // transpose from per-channel regs
            tt.x = t0[i]; tt.y = t1[i]; tt.z = t2[i]; tt.w = t3[i];
            v4f mm;
            mm.x = fmaxf(xv.x * tt.x, 0.0f) * ct.x;
            mm.y = fmaxf(xv.y * tt.y, 0.0f) * ct.y;
            mm.z = fmaxf(xv.z * tt.z, 0.0f) * ct.z;
            mm.w = fmaxf(xv.w * tt.w, 0.0f) * ct.w;
            __builtin_nontemporal_store(mm, (v4f*)(out_m + (size_t)i * C));
            __builtin_nontemporal_store(xv, (v4f*)(out_x + (size_t)i * C));
            __builtin_nontemporal_store(tt, (v4f*)(out_t + (size_t)i * C));
        }
    }

    // ---- tail position se (waves 6,7 only; wave-uniform branch) -----------
    if (xtra) {
        v4f tt;
        tt.x = t_p[off.x + se];
        tt.y = t_p[off.y + se];
        tt.z = t_p[off.z + se];
        tt.w = t_p[off.w + se];
        v4f ct = *(const v4f*)(ctp + (size_t)se * C + c0);
        v4f mm;
        mm.x = fmaxf(xe.x * tt.x, 0.0f) * ct.x;
        mm.y = fmaxf(xe.y * tt.y, 0.0f) * ct.y;
        mm.z = fmaxf(xe.z * tt.z, 0.0f) * ct.z;
        mm.w = fmaxf(xe.w * tt.w, 0.0f) * ct.w;
        const size_t base = ((size_t)b * HW + se) * C + c0;
        __builtin_nontemporal_store(mm, (v4f*)(out + base));
        __builtin_nontemporal_store(xe, (v4f*)(out + plane + base));
        __builtin_nontemporal_store(tt, (v4f*)(out + 2 * plane + base));
    }
}

// ---------------------------------------------------------------------------
extern "C" void kernel_launch(void* const* d_in, const int* in_sizes, int n_in,
                              void* d_out, int out_size, void* d_ws, size_t ws_size,
                              hipStream_t stream) {
    const float* x    = (const float*)d_in[0];  // [B,H,W,C]
    const float* gt   = (const float*)d_in[1];  // [B,NCLS]
    const float* t_p  = (const float*)d_in[2];  // [15,15,H,W]
    const float* ctpl = (const float*)d_in[3];  // [NCLS,H,W,C]
    float* out = (float*)d_out;                 // [3, B,H,W,C] flat

    hipLaunchKernelGGL(fused_kernel,
                       dim3(4 * B), dim3(512), 0, stream,
                       x, gt, t_p, ctpl, out);
}

// Round 8
// 250.971 us; speedup vs baseline: 1.0341x; 1.0341x over previous
//
#include <hip/hip_runtime.h>

// Problem constants (from reference setup_inputs)
#define B    128
#define H    14
#define W    14
#define C    512
#define NCLS 200
#define HW   (H * W)          // 196
#define TP_DIM 15             // t_p is [15,15,14,14]
#define SENT_OFF ((14 * TP_DIM + 14) * HW)  // sentinel template row offset

typedef float  v4f __attribute__((ext_vector_type(4)));
typedef int    v4i __attribute__((ext_vector_type(4)));

// ---------------------------------------------------------------------------
// Fused kernel v8 = v4 (best, 250.3) + out_x stream fused into phase 1.
//
// Differential evidence r4..r7: LDS-staged t_p tile is the only win (-10);
// x-in-registers and occupancy changes are nulls/regressions. v8 reverts to
// v4's exact structure and changes ONE thing: the out_x plane (pure copy of
// x) is stored in phase 1, straight from the argmax registers — moving 51.4
// MB of stores into the otherwise store-idle phase-1 latency window and
// cutting phase-2 stores from 12 to 8 per quad. Secondary micro: the
// argmax combine runs on 128 threads (scalar per channel, stride-1 LDS =
// 2-way = free) instead of 32.
//
// Structure (per block = batch b x channel-quarter, 512 blocks x 512 thr):
//   Phase 1: thread (sl<14, cg) loads x[14sl..14sl+13][c0..c0+3] (14 v4f),
//     nontemporal-stores them to out_x, folds argmax (ascending s, strict >).
//     Wave 7 concurrently argmaxes gt[b] (index-min tie-break).
//   Combine: 128 threads, one channel each, fold 14 slices ascending ->
//     t_p row offsets in s_off.
//   Phase 2 (two spatial halves): cooperative stage of the 128 gathered
//     t_p rows into LDS t_tile[s][c] (kills divergent gathers in the hot
//     loop), then per-quad: 4 ld x (L2-warm) + 4 ld ctpl + 4 ds_read_b128
//     + 8 nontemporal stores (out_m, out_t).
//   XCD swizzle: quarter-blocks of batch b share blockIdx mod 8 -> one L2
//     fetch of the 401 KB ctpl class row per XCD.
// ---------------------------------------------------------------------------
__global__ __launch_bounds__(512) void fused_kernel(
        const float* __restrict__ x,
        const float* __restrict__ gt,
        const float* __restrict__ t_p,
        const float* __restrict__ ctpl,
        float*       __restrict__ out) {
    __shared__ union SMem {
        struct { v4f best[14][32]; v4i idx[14][32]; } ph1;  // 14,336 B
        float t_tile[100][128];                              // 51,200 B
    } smem;
    __shared__ int s_off[128];
    __shared__ int s_cls;

    const int tid     = threadIdx.x;
    const int b       = blockIdx.x & 127;   // XCD swizzle (see header)
    const int quarter = blockIdx.x >> 7;
    const int cg      = tid & 31;     // channel group (4 channels) 0..31
    const int sl      = tid >> 5;     // slice / quad-slot id 0..15
    const int c0      = quarter * 128 + cg * 4;   // global channel base
    const int cl      = cg * 4;                   // local channel base

    const size_t plane = (size_t)B * HW * C;
    const float* __restrict__ xp  = x   + (size_t)b * HW * C + c0;
    float*       __restrict__ oxp = out + plane + (size_t)b * HW * C + c0;

    // ---------------- Phase 1: argmax + out_x stream ------------------------
    if (sl < 14) {
        // spatial slice 14*sl .. 14*sl+13 for channels c0..c0+3
        const int sbeg = sl * 14;
        v4f xr[14];
#pragma unroll
        for (int k = 0; k < 14; ++k)
            xr[k] = *(const v4f*)(xp + (size_t)(sbeg + k) * C);
        // out_x = x, straight from registers, during the latency-bound phase
#pragma unroll
        for (int k = 0; k < 14; ++k)
            __builtin_nontemporal_store(xr[k], (v4f*)(oxp + (size_t)(sbeg + k) * C));

        v4f best = xr[0];
        v4i bidx = (v4i){sbeg, sbeg, sbeg, sbeg};
#pragma unroll
        for (int k = 1; k < 14; ++k) {
            const int s = sbeg + k;
            v4f v = xr[k];
            if (v.x > best.x) { best.x = v.x; bidx.x = s; }  // strict > = first occ.
            if (v.y > best.y) { best.y = v.y; bidx.y = s; }
            if (v.z > best.z) { best.z = v.z; bidx.z = s; }
            if (v.w > best.w) { best.w = v.w; bidx.w = s; }
        }
        smem.ph1.best[sl][cg] = best;
        smem.ph1.idx[sl][cg]  = bidx;
    } else {
        // wave 7 (tid 448..511): class argmax over gt[b], index-min tie-break
        const int lane = tid - 448;
        const float* __restrict__ g = gt + (size_t)b * NCLS;
        float gb = -__builtin_inff();
        int   gi = NCLS;
        for (int i = lane; i < NCLS; i += 64) {   // ascending per lane
            float v = g[i];
            if (v > gb) { gb = v; gi = i; }       // keeps smallest index
        }
#pragma unroll
        for (int d = 1; d < 64; d <<= 1) {
            float ov = __shfl_xor(gb, d);
            int   oi = __shfl_xor(gi, d);
            if (ov > gb || (ov == gb && oi < gi)) { gb = ov; gi = oi; }
        }
        if (lane == 0) s_cls = gi;
    }
    __syncthreads();

    // ---------------- Combine: 128 threads, one channel each ---------------
    if (tid < 128) {
        const float* bf = (const float*)smem.ph1.best;  // [14][128] floats
        const int*   qf = (const int*)smem.ph1.idx;     // [14][128] ints
        float cb = bf[tid];
        int   ci = qf[tid];
#pragma unroll
        for (int k = 1; k < 14; ++k) {          // ascending s: '>' keeps first
            float p = bf[k * 128 + tid];
            int   q = qf[k * 128 + tid];
            if (p > cb) { cb = p; ci = q; }
        }
        s_off[tid] = (cb == 0.0f) ? SENT_OFF
                                  : ((ci / W) * TP_DIM + (ci % W)) * HW;
    }
    __syncthreads();   // s_off visible; ph1 scratch dead -> t_tile may alias

    const int klass = s_cls;
    const float* __restrict__ ctp = ctpl + (size_t)klass * HW * C;

    // stage: copy t_p rows (contiguous, L2-resident) into LDS [s][c_local].
    // thread t: local channel r = t>>2, v4f chunk ids j ≡ (t&3) mod 4.
    const int r = tid >> 2;
    const int p = tid & 3;
    const float* __restrict__ trow = t_p + s_off[r];

    auto stage = [&](int jbeg, int jend, int sbase) {
        for (int j = jbeg + p; j < jend; j += 4) {
            v4f v = *(const v4f*)(trow + j * 4);   // 16-B aligned (off%4==0)
            const int s = j * 4 - sbase;
            smem.t_tile[s + 0][r] = v.x;
            smem.t_tile[s + 1][r] = v.y;
            smem.t_tile[s + 2][r] = v.z;
            smem.t_tile[s + 3][r] = v.w;
        }
    };

    auto process_quad = [&](int q, int sbase) {
        const int s0 = q * 4;
        v4f tvv[4];
#pragma unroll
        for (int i = 0; i < 4; ++i)   // lanes contiguous in c
            tvv[i] = *(const v4f*)&smem.t_tile[s0 - sbase + i][cl];

        const size_t base = ((size_t)b * HW + s0) * C + c0;
        const float* __restrict__ xq = x + base;
        const float* __restrict__ cp = ctp + (size_t)s0 * C + c0;
        float* __restrict__ out_m = out + base;
        float* __restrict__ out_t = out + 2 * plane + base;

#pragma unroll
        for (int i = 0; i < 4; ++i) {
            v4f xv = *(const v4f*)(xq + (size_t)i * C);   // L2-warm re-read
            v4f ct = *(const v4f*)(cp + (size_t)i * C);
            v4f tt = tvv[i];
            v4f mm;
            mm.x = fmaxf(xv.x * tt.x, 0.0f) * ct.x;
            mm.y = fmaxf(xv.y * tt.y, 0.0f) * ct.y;
            mm.z = fmaxf(xv.z * tt.z, 0.0f) * ct.z;
            mm.w = fmaxf(xv.w * tt.w, 0.0f) * ct.w;
            __builtin_nontemporal_store(mm, (v4f*)(out_m + (size_t)i * C));
            __builtin_nontemporal_store(tt, (v4f*)(out_t + (size_t)i * C));
        }
    };

    // ---- half 0: quads 0..23 (spatial 0..95) ------------------------------
    stage(0, 24, 0);
    __syncthreads();
    process_quad(sl, 0);                       // q = 0..15
    if (sl < 8) process_quad(sl + 16, 0);      // q = 16..23
    __syncthreads();

    // ---- half 1: quads 24..48 (spatial 96..195) ---------------------------
    stage(24, 49, 96);
    __syncthreads();
    process_quad(24 + sl, 96);                 // q = 24..39
    if (sl <= 8) process_quad(40 + sl, 96);    // q = 40..48
}

// ---------------------------------------------------------------------------
extern "C" void kernel_launch(void* const* d_in, const int* in_sizes, int n_in,
                              void* d_out, int out_size, void* d_ws, size_t ws_size,
                              hipStream_t stream) {
    const float* x    = (const float*)d_in[0];  // [B,H,W,C]
    const float* gt   = (const float*)d_in[1];  // [B,NCLS]
    const float* t_p  = (const float*)d_in[2];  // [15,15,H,W]
    const float* ctpl = (const float*)d_in[3];  // [NCLS,H,W,C]
    float* out = (float*)d_out;                 // [3, B,H,W,C] flat

    hipLaunchKernelGGL(fused_kernel,
                       dim3(4 * B), dim3(512), 0, stream,
                       x, gt, t_p, ctpl, out);
}